// Round 8
// baseline (161.060 us; speedup 1.0000x reference)
//
#include <hip/hip_runtime.h>

// GNN layer: out = segment_sum(nf[src], dst) @ W.T + b
// N=50000, E=800000, D=128.
// R21: deep async gather = R18's global_load_lds mechanism (no VGPR result
// -> compiler can't sink it; depth set by counted vmcnt) + R14's parallel
// consume + real depth. 7-round model: gather is MLP-bound (~30 lines in
// flight/CU at ~600cy IC latency); hipcc pins register-pipelines to ~2 deep
// (R15/16/17), so depth must come from LDS staging. Phase B per wave
// (4 nodes, BS=32, 512thr): ring of 4 x 2KB chunk slots; chunk = 8 edges =
// 2 x global_load_lds_dwordx4; issue 3 chunks ahead ACROSS node boundaries
// (6KB/wave in flight, x16 waves/CU ~= 96KB/CU vs ~4KB today); vmcnt(4/2/0)
// counted, never drained mid-stream. Consume wave-parallel: lane (e,d) reads
// 32B of edge e via 2 x ds_read_b128; parity-XOR source-slot pre-swizzle
// (m173; LDS dest must stay linear per m104) makes reads bank-uniform
// (naive layout = 16-way conflict). Node end: shfl_xor(8,16,32) butterfly,
// 8 lanes write the 256B tile row. Per-node state read live from LDS
// (rule #20: no runtime-indexed register arrays). A/C phases + producer =
// R19 verbatim (best core, 45.0us).

constexpr int NN = 50000;
constexpr int NE = 800000;
constexpr int D  = 128;

constexpr int BS   = 32;                       // nodes per bucket
constexpr int NB   = (NN + BS - 1) / BS;       // 1563 buckets
constexpr int EPB  = 4096;                     // edges per producer block
constexpr int NSB  = (NE + EPB - 1) / EPB;     // 196 producer blocks
constexpr int CAP  = 1024;                     // per-bucket edge cap (avg 512)

constexpr int AROWU = 136;                     // tile row stride (ushorts)

typedef __attribute__((ext_vector_type(8))) short bf16x8;
typedef __attribute__((ext_vector_type(4))) float f32x4;
typedef __attribute__((ext_vector_type(2))) float f32x2;

__device__ inline unsigned short f2bf(float f) {           // RNE
    unsigned u = __float_as_uint(f);
    return (unsigned short)((u + 0x7fffu + ((u >> 16) & 1u)) >> 16);
}
__device__ inline float bflo(unsigned v) { return __uint_as_float(v << 16); }
__device__ inline float bfhi(unsigned v) { return __uint_as_float(v & 0xffff0000u); }
__device__ inline unsigned pk2(f32x2 a) {
    return (unsigned)f2bf(a.x) | ((unsigned)f2bf(a.y) << 16);
}

__device__ inline int wscan(int v) {           // wave-inclusive scan (64)
    #pragma unroll
    for (int o = 1; o < 64; o <<= 1) {
        int u = __shfl_up(v, o);
        if ((int)(threadIdx.x & 63) >= o) v += u;
    }
    return v;
}

__device__ inline void red3(f32x2& a) {        // allreduce over lane>>3 axis
    a.x += __shfl_xor(a.x, 8);  a.y += __shfl_xor(a.y, 8);
    a.x += __shfl_xor(a.x, 16); a.y += __shfl_xor(a.y, 16);
    a.x += __shfl_xor(a.x, 32); a.y += __shfl_xor(a.y, 32);
}

// async 16B/lane gather into LDS (linear dest: base + lane*16)
__device__ __forceinline__ void gl_lds16(const unsigned* g, unsigned* l) {
    __builtin_amdgcn_global_load_lds(
        (const __attribute__((address_space(1))) unsigned*)g,
        (__attribute__((address_space(3))) unsigned*)l, 16, 0, 0);
}
#define WAITVM4() { asm volatile("s_waitcnt vmcnt(4)" ::: "memory"); \
                    __builtin_amdgcn_sched_barrier(0); }
#define WAITVM2() { asm volatile("s_waitcnt vmcnt(2)" ::: "memory"); \
                    __builtin_amdgcn_sched_barrier(0); }
#define WAITVM0() { asm volatile("s_waitcnt vmcnt(0)" ::: "memory"); \
                    __builtin_amdgcn_sched_barrier(0); }

// ---- 1. fused prep (bf16 cvt) + bucket-sort partition ---------------------
constexpr int NF4 = NN * D / 4;                           // 1,600,000
constexpr int W4  = D * D / 4;                            // 4,096
constexpr int NBLK_P = (NF4 + W4 + 511) / 512;            // 3134
constexpr int GRID_A = NSB + NBLK_P;

__global__ __launch_bounds__(512) void k_prep_bucket(
    const float* __restrict__ nf, const float* __restrict__ W,
    const int* __restrict__ ei,
    ushort* __restrict__ nfh, ushort* __restrict__ Wh,
    ushort* __restrict__ offs, unsigned* __restrict__ buf)
{
    __shared__ int hist[NB], cur[NB];              // 12.5 KB
    __shared__ int wsum[8];
    __shared__ unsigned spk[EPB];                  // 16384 B
    const int t = threadIdx.x, lane = t & 63, w = t >> 6;

    if (blockIdx.x < NSB) {
        const int blk = blockIdx.x;
        const int e0  = blk * EPB;
        int cnt = NE - e0; if (cnt > EPB) cnt = EPB;

        for (int i = t; i < NB; i += 512) hist[i] = 0;
        __syncthreads();

        unsigned pk[8];
        #pragma unroll
        for (int j = 0; j < 8; ++j) {
            int idx = j * 512 + t;
            if (idx < cnt) {
                int e = e0 + idx;
                unsigned s = (unsigned)ei[e];
                unsigned d = (unsigned)ei[NE + e];
                pk[j] = (d << 16) | s;             // bucket = pk >> 21 (BS=32)
                atomicAdd(&hist[pk[j] >> 21], 1);
            }
        }
        __syncthreads();
        // 4-bins/thread wave shfl scan over 1563 bins
        const int base = 4 * t;
        int h0 = (base     < NB) ? hist[base]     : 0;
        int h1 = (base + 1 < NB) ? hist[base + 1] : 0;
        int h2 = (base + 2 < NB) ? hist[base + 2] : 0;
        int h3 = (base + 3 < NB) ? hist[base + 3] : 0;
        int s4 = h0 + h1 + h2 + h3;
        int v = wscan(s4);
        if (lane == 63) wsum[w] = v;
        __syncthreads();
        int addv = 0;
        #pragma unroll
        for (int i = 0; i < 8; ++i) addv += (i < w) ? wsum[i] : 0;
        v += addv;                                 // inclusive through base+3
        int e0b = v - s4, e1b = e0b + h0, e2b = e1b + h1, e3b = e2b + h2;
        if (base     < NB) { cur[base]     = e0b; offs[(base    ) * NSB + blk] = (ushort)e0b; }
        if (base + 1 < NB) { cur[base + 1] = e1b; offs[(base + 1) * NSB + blk] = (ushort)e1b; }
        if (base + 2 < NB) { cur[base + 2] = e2b; offs[(base + 2) * NSB + blk] = (ushort)e2b; }
        if (base + 3 < NB) { cur[base + 3] = e3b; offs[(base + 3) * NSB + blk] = (ushort)e3b; }
        if (t == 0) offs[NB * NSB + blk] = (ushort)cnt;
        __syncthreads();
        #pragma unroll
        for (int j = 0; j < 8; ++j) {
            int idx = j * 512 + t;
            if (idx < cnt) {
                int l = atomicAdd(&cur[pk[j] >> 21], 1);
                spk[l] = pk[j];
            }
        }
        __syncthreads();
        for (int i = t; i < cnt; i += 512)         // dense coalesced 16KB
            buf[(size_t)blk * EPB + i] = spk[i];
    } else {
        // prep branch: bf16 conversion
        int i = (blockIdx.x - NSB) * 512 + t;
        if (i < NF4) {
            float4 v = ((const float4*)nf)[i];
            ((ushort4*)nfh)[i] = make_ushort4(f2bf(v.x), f2bf(v.y), f2bf(v.z), f2bf(v.w));
        } else if (i < NF4 + W4) {
            int k = i - NF4;
            float4 v = ((const float4*)W)[k];
            ((ushort4*)Wh)[k] = make_ushort4(f2bf(v.x), f2bf(v.y), f2bf(v.z), f2bf(v.w));
        }
    }
}

// ---- 2. fused gather-sort + aggregate + linear ----------------------------
__global__ __launch_bounds__(512) void k_sort_agg(
    const unsigned* __restrict__ nfh, const unsigned* __restrict__ buf,
    const ushort* __restrict__ offs, const ushort* __restrict__ Wh,
    const float* __restrict__ bias, float* __restrict__ out)
{
    __shared__ ushort srt[CAP];                     // 2048 B
    __shared__ int scnt[256];                       // 1024 B
    __shared__ int sbase[NSB], rbase[NSB];          // 1568 B
    __shared__ int hist[BS], off[BS], cur[BS];      // 384 B
    __shared__ int wred[16];
    __shared__ __align__(16) unsigned tile[BS * AROWU / 2];  // 8704 B
    __shared__ __align__(16) unsigned stag[8][2048];         // 65536 B ring
    const int b = blockIdx.x, t = threadIdx.x;
    const int lane = t & 63, w = t >> 6;

    // --- Phase A1: per-producer run bases/counts -> wave shfl scan
    int my = 0;
    if (t < NSB) {
        int o0 = (int)offs[b * NSB + t];           // coalesced 392B row
        int o1 = (int)offs[(b + 1) * NSB + t];
        rbase[t] = o0;
        my = o1 - o0;
    }
    if (t < BS) hist[t] = 0;
    int vs = 0;
    if (w < 4) {
        vs = wscan(my);
        if (lane == 63) wred[w] = vs;
    }
    __syncthreads();
    if (w < 4) {
        int addv = 0;
        #pragma unroll
        for (int i = 0; i < 3; ++i) addv += (i < w) ? wred[i] : 0;
        vs += addv;
        scnt[t] = vs;                              // global inclusive
        if (t < NSB) sbase[t] = vs - my;
    }
    __syncthreads();
    int total = scnt[NSB - 1];
    if (total > CAP) total = CAP;                  // defensive

    // --- Phase A2: pk in registers + node histogram
    unsigned mypk[2];
    int mycnt = 0;
    #pragma unroll
    for (int j = 0; j < 2; ++j) {
        int p = t + j * 512;
        if (p < total) {
            int lo = 0, hi = NSB - 1;              // min i: scnt[i] > p
            while (lo < hi) {
                int mid = (lo + hi) >> 1;
                if (scnt[mid] > p) hi = mid; else lo = mid + 1;
            }
            unsigned pk = buf[(size_t)lo * EPB + rbase[lo] + (p - sbase[lo])];
            mypk[j] = pk;
            atomicAdd(&hist[(pk >> 16) & (BS - 1)], 1);
            mycnt = j + 1;
        }
    }
    __syncthreads();

    // --- Phase A3: 32-bin scan (single wave) + scatter into srt (local CSR)
    int hv = (t < BS) ? hist[t] : 0;
    int nv = 0;
    if (w == 0) nv = wscan(hv);
    __syncthreads();
    if (t < BS) { int ex = nv - hv; off[t] = ex; cur[t] = ex; }
    __syncthreads();
    #pragma unroll
    for (int j = 0; j < 2; ++j) {
        if (j < mycnt) {
            unsigned pk = mypk[j];
            int n = (pk >> 16) & (BS - 1);
            int p = atomicAdd(&cur[n], 1);
            srt[p] = (ushort)(pk & 0xffffu);
        }
    }
    __syncthreads();

    // --- Phase B: deep async gather. Wave w owns nodes wn0..wn0+3.
    // Chunk = 8 edges = 2KB = 2 x global_load_lds_dwordx4; 4-slot ring;
    // up to 3 chunks in flight across node boundaries; counted vmcnt.
    const int qq = lane >> 4, sl = lane & 15;      // write-side mapping
    const int eL = lane >> 3, dL = lane & 7;       // read-side mapping
    const unsigned* nfu = nfh;                     // row = 64 u32
    unsigned* stagw = stag[w];
    const int wn0 = w * 4;

    int is_n = 0, is_c = 0, fi_issue = 0;
    auto adv = [&]() {
        while (is_n < 4) {
            int ct = hist[wn0 + is_n];
            if (is_c < ((ct + 7) >> 3)) break;
            ++is_n; is_c = 0;
        }
    };
    auto issue1 = [&]() {                          // cursor valid on entry
        const int beg = off[wn0 + is_n];
        const int lim = beg + hist[wn0 + is_n] - 1;
        unsigned* dst = stagw + (fi_issue & 3) * 512;
        #pragma unroll
        for (int j = 0; j < 2; ++j) {
            const int ec = 4 * j + qq;             // edge-in-chunk 0..7
            int e = beg + is_c * 8 + ec;
            if (e > lim) e = lim;                  // clamped dup (masked later)
            const int gslot = sl ^ (ec << 1);      // parity-XOR pre-swizzle
            gl_lds16(nfu + (size_t)srt[e] * 64 + gslot * 4, dst + j * 256);
        }
        ++fi_issue; ++is_c; adv();
    };
    adv();
    if (is_n < 4) issue1();
    if (is_n < 4) issue1();
    if (is_n < 4) issue1();

    int fi = 0;
    #pragma unroll 1
    for (int n = 0; n < 4; ++n) {
        f32x2 a0 = {0.f,0.f}, a1 = {0.f,0.f}, a2 = {0.f,0.f}, a3 = {0.f,0.f};
        f32x2 a4 = {0.f,0.f}, a5 = {0.f,0.f}, a6 = {0.f,0.f}, a7 = {0.f,0.f};
        const int cnt = hist[wn0 + n];
        const int nc = (cnt + 7) >> 3;
        #pragma unroll 1
        for (int c = 0; c < nc; ++c, ++fi) {
            const int ahead = fi_issue - fi;       // 1..3
            if (ahead >= 3)      WAITVM4()
            else if (ahead == 2) WAITVM2()
            else                 WAITVM0()
            if (is_n < 4) issue1();                // refill ring ASAP
            // read chunk fi (slot fi&3): lane (eL,dL) takes 32B of edge eL.
            // parity layout: both b128 reads hit all 8 bank-groups evenly.
            const int ro  = (fi & 3) * 512 + eL * 64 + ((dL ^ eL) << 3);
            const int par = (eL & 1) << 2;         // 0 or 4 u32
            uint4 xa = *(const uint4*)(stagw + ro + par);
            uint4 xb = *(const uint4*)(stagw + ro + 4 - par);
            uint4 lo = (eL & 1) ? xb : xa;         // global slot 2d
            uint4 hi = (eL & 1) ? xa : xb;         // global slot 2d+1
            int kmax = cnt - 8 * c; if (kmax > 8) kmax = 8;
            if (eL < kmax) {                       // mask clamped dups
                a0 += (f32x2){bflo(lo.x), bfhi(lo.x)};
                a1 += (f32x2){bflo(lo.y), bfhi(lo.y)};
                a2 += (f32x2){bflo(lo.z), bfhi(lo.z)};
                a3 += (f32x2){bflo(lo.w), bfhi(lo.w)};
                a4 += (f32x2){bflo(hi.x), bfhi(hi.x)};
                a5 += (f32x2){bflo(hi.y), bfhi(hi.y)};
                a6 += (f32x2){bflo(hi.z), bfhi(hi.z)};
                a7 += (f32x2){bflo(hi.w), bfhi(hi.w)};
            }
        }
        // allreduce over edge axis (lanes l, l^8, l^16, l^32)
        red3(a0); red3(a1); red3(a2); red3(a3);
        red3(a4); red3(a5); red3(a6); red3(a7);
        if (lane < 8) {                            // lane d writes dims 16d..
            unsigned* tr = tile + (wn0 + n) * (AROWU / 2) + lane * 8;
            uint4 o1, o2;
            o1.x = pk2(a0); o1.y = pk2(a1); o1.z = pk2(a2); o1.w = pk2(a3);
            o2.x = pk2(a4); o2.y = pk2(a5); o2.z = pk2(a6); o2.w = pk2(a7);
            *(uint4*)tr = o1;
            *(uint4*)(tr + 4) = o2;
        }
    }
    __syncthreads();

    // --- Phase C: 2 row-tiles x 8 col-chunks = 16 MFMA tasks over 8 waves
    const int m = lane & 15, q = lane >> 4;
    const ushort* lds = (const ushort*)tile;
    #pragma unroll
    for (int i = 0; i < 2; ++i) {
        const int task = w + 8 * i;                 // 0..15, bijective
        const int t16  = task >> 3;                 // row-tile 0..1
        const int c0   = (task & 7) * 16;           // col chunk
        const int grow0 = b * BS + t16 * 16;
        if (grow0 < NN) {                           // last bucket: 1 full tile
            bf16x8 a[4];
            const ushort* arow = lds + (t16 * 16 + m) * AROWU + q * 8;
            #pragma unroll
            for (int kk = 0; kk < 4; ++kk)
                a[kk] = *(const bf16x8*)(arow + kk * 32);
            float bv = bias[c0 + m];
            f32x4 acc4 = { bv, bv, bv, bv };
            const ushort* wrow = Wh + (size_t)(c0 + m) * D + q * 8;
            #pragma unroll
            for (int kk = 0; kk < 4; ++kk) {
                bf16x8 bb = *(const bf16x8*)(wrow + kk * 32);
                acc4 = __builtin_amdgcn_mfma_f32_16x16x32_bf16(a[kk], bb, acc4, 0, 0, 0);
            }
            float* op = out + (size_t)(grow0 + q * 4) * D + c0 + m;
            op[0]     = acc4[0];
            op[D]     = acc4[1];
            op[2 * D] = acc4[2];
            op[3 * D] = acc4[3];
        }
    }
}

extern "C" void kernel_launch(void* const* d_in, const int* in_sizes, int n_in,
                              void* d_out, int out_size, void* d_ws, size_t ws_size,
                              hipStream_t stream) {
    const float* nf = (const float*)d_in[0];
    const int*   ei = (const int*)d_in[1];
    const float* W  = (const float*)d_in[2];
    const float* b  = (const float*)d_in[3];
    float* out = (float*)d_out;

    // workspace (~16.7 MB)
    ushort*   nfh  = (ushort*)d_ws;                    // NN*D bf16 = 12.8 MB
    ushort*   Wh   = nfh + (size_t)NN * D;             // 32 KB
    unsigned* buf  = (unsigned*)(Wh + D * D);          // NSB*EPB u32 = 3.2 MB
    ushort*   offs = (ushort*)(buf + (size_t)NSB * EPB); // (NB+1)*NSB = 613 KB

    k_prep_bucket<<<GRID_A, 512, 0, stream>>>(nf, W, ei, nfh, Wh, offs, buf);
    k_sort_agg   <<<NB, 512, 0, stream>>>((const unsigned*)nfh, buf, offs, Wh, b, out);
}

// Round 9
// 131.702 us; speedup vs baseline: 1.2229x; 1.2229x over previous
//
#include <hip/hip_runtime.h>

// GNN layer: out = segment_sum(nf[src], dst) @ W.T + b
// N=50000, E=800000, D=128.
// R22: A-phase shave on the best core (R19, sort 45.0us). 9-round ledger:
// all Phase-B "depth" attempts fail (compiler sinks reg pipelines R15/16/17;
// async-LDS consume overhead eats the gain R18/R21); best rate comes from
// many simple waves. Remaining proven overhead: A2's binary search = 8
// dependent ds_read (~1000cy) per THREAD + scattered buf gather, x1563
// blocks, barrier-bounded (occ 54%). Fix: direct per-run copy -- thread t
// (<196) copies its contiguous run buf[t*EPB+rbase[t]..+my] into LDS
// pkbuf[sbase[t]+k] (positions known from A1 scan, no search, no scatter
// gather), histogramming on the fly; A3 scatters from pkbuf (2 edges/thr).
// +4KB LDS (17.9KB, still 4 blocks/CU wave-limited). Phase B/C + producer
// = R19 verbatim.

constexpr int NN = 50000;
constexpr int NE = 800000;
constexpr int D  = 128;

constexpr int BS   = 32;                       // nodes per bucket
constexpr int NB   = (NN + BS - 1) / BS;       // 1563 buckets
constexpr int EPB  = 4096;                     // edges per producer block
constexpr int NSB  = (NE + EPB - 1) / EPB;     // 196 producer blocks
constexpr int CAP  = 1024;                     // per-bucket edge cap (avg 512)

constexpr int AROWU = 136;                     // tile row stride (ushorts)

typedef __attribute__((ext_vector_type(8))) short bf16x8;
typedef __attribute__((ext_vector_type(4))) float f32x4;
typedef __attribute__((ext_vector_type(2))) float f32x2;

__device__ inline unsigned short f2bf(float f) {           // RNE
    unsigned u = __float_as_uint(f);
    return (unsigned short)((u + 0x7fffu + ((u >> 16) & 1u)) >> 16);
}
__device__ inline float bflo(unsigned v) { return __uint_as_float(v << 16); }
__device__ inline float bfhi(unsigned v) { return __uint_as_float(v & 0xffff0000u); }

__device__ inline int wscan(int v) {           // wave-inclusive scan (64)
    #pragma unroll
    for (int o = 1; o < 64; o <<= 1) {
        int u = __shfl_up(v, o);
        if ((int)(threadIdx.x & 63) >= o) v += u;
    }
    return v;
}

__device__ inline void acc8(f32x2& a0, f32x2& a1, f32x2& a2, f32x2& a3, uint4 v) {
    a0 += (f32x2){bflo(v.x), bfhi(v.x)};
    a1 += (f32x2){bflo(v.y), bfhi(v.y)};
    a2 += (f32x2){bflo(v.z), bfhi(v.z)};
    a3 += (f32x2){bflo(v.w), bfhi(v.w)};
}

// ---- 1. fused prep (bf16 cvt) + bucket-sort partition ---------------------
constexpr int NF4 = NN * D / 4;                           // 1,600,000
constexpr int W4  = D * D / 4;                            // 4,096
constexpr int NBLK_P = (NF4 + W4 + 511) / 512;            // 3134
constexpr int GRID_A = NSB + NBLK_P;

__global__ __launch_bounds__(512) void k_prep_bucket(
    const float* __restrict__ nf, const float* __restrict__ W,
    const int* __restrict__ ei,
    ushort* __restrict__ nfh, ushort* __restrict__ Wh,
    ushort* __restrict__ offs, unsigned* __restrict__ buf)
{
    __shared__ int hist[NB], cur[NB];              // 12.5 KB
    __shared__ int wsum[8];
    __shared__ unsigned spk[EPB];                  // 16384 B
    const int t = threadIdx.x, lane = t & 63, w = t >> 6;

    if (blockIdx.x < NSB) {
        const int blk = blockIdx.x;
        const int e0  = blk * EPB;
        int cnt = NE - e0; if (cnt > EPB) cnt = EPB;

        for (int i = t; i < NB; i += 512) hist[i] = 0;
        __syncthreads();

        unsigned pk[8];
        #pragma unroll
        for (int j = 0; j < 8; ++j) {
            int idx = j * 512 + t;
            if (idx < cnt) {
                int e = e0 + idx;
                unsigned s = (unsigned)ei[e];
                unsigned d = (unsigned)ei[NE + e];
                pk[j] = (d << 16) | s;             // bucket = pk >> 21 (BS=32)
                atomicAdd(&hist[pk[j] >> 21], 1);
            }
        }
        __syncthreads();
        // 4-bins/thread wave shfl scan over 1563 bins
        const int base = 4 * t;
        int h0 = (base     < NB) ? hist[base]     : 0;
        int h1 = (base + 1 < NB) ? hist[base + 1] : 0;
        int h2 = (base + 2 < NB) ? hist[base + 2] : 0;
        int h3 = (base + 3 < NB) ? hist[base + 3] : 0;
        int s4 = h0 + h1 + h2 + h3;
        int v = wscan(s4);
        if (lane == 63) wsum[w] = v;
        __syncthreads();
        int addv = 0;
        #pragma unroll
        for (int i = 0; i < 8; ++i) addv += (i < w) ? wsum[i] : 0;
        v += addv;                                 // inclusive through base+3
        int e0b = v - s4, e1b = e0b + h0, e2b = e1b + h1, e3b = e2b + h2;
        if (base     < NB) { cur[base]     = e0b; offs[(base    ) * NSB + blk] = (ushort)e0b; }
        if (base + 1 < NB) { cur[base + 1] = e1b; offs[(base + 1) * NSB + blk] = (ushort)e1b; }
        if (base + 2 < NB) { cur[base + 2] = e2b; offs[(base + 2) * NSB + blk] = (ushort)e2b; }
        if (base + 3 < NB) { cur[base + 3] = e3b; offs[(base + 3) * NSB + blk] = (ushort)e3b; }
        if (t == 0) offs[NB * NSB + blk] = (ushort)cnt;
        __syncthreads();
        #pragma unroll
        for (int j = 0; j < 8; ++j) {
            int idx = j * 512 + t;
            if (idx < cnt) {
                int l = atomicAdd(&cur[pk[j] >> 21], 1);
                spk[l] = pk[j];
            }
        }
        __syncthreads();
        for (int i = t; i < cnt; i += 512)         // dense coalesced 16KB
            buf[(size_t)blk * EPB + i] = spk[i];
    } else {
        // prep branch: bf16 conversion
        int i = (blockIdx.x - NSB) * 512 + t;
        if (i < NF4) {
            float4 v = ((const float4*)nf)[i];
            ((ushort4*)nfh)[i] = make_ushort4(f2bf(v.x), f2bf(v.y), f2bf(v.z), f2bf(v.w));
        } else if (i < NF4 + W4) {
            int k = i - NF4;
            float4 v = ((const float4*)W)[k];
            ((ushort4*)Wh)[k] = make_ushort4(f2bf(v.x), f2bf(v.y), f2bf(v.z), f2bf(v.w));
        }
    }
}

// ---- 2. fused gather-sort + aggregate + linear ----------------------------
__global__ __launch_bounds__(512) void k_sort_agg(
    const unsigned* __restrict__ nfh, const unsigned* __restrict__ buf,
    const ushort* __restrict__ offs, const ushort* __restrict__ Wh,
    const float* __restrict__ bias, float* __restrict__ out)
{
    __shared__ ushort srt[CAP];                     // 2048 B
    __shared__ unsigned pkbuf[CAP];                 // 4096 B
    __shared__ int scnt[256];                       // 1024 B
    __shared__ int sbase[NSB], rbase[NSB];          // 1568 B
    __shared__ int hist[BS], off[BS], cur[BS];      // 384 B
    __shared__ int wred[16];
    __shared__ __align__(16) unsigned tile[BS * AROWU / 2];  // 8704 B (~18KB)
    const int b = blockIdx.x, t = threadIdx.x;
    const int lane = t & 63, w = t >> 6;

    // --- Phase A1: per-producer run bases/counts -> wave shfl scan
    int my = 0;
    if (t < NSB) {
        int o0 = (int)offs[b * NSB + t];           // coalesced 392B row
        int o1 = (int)offs[(b + 1) * NSB + t];
        rbase[t] = o0;
        my = o1 - o0;
    }
    if (t < BS) hist[t] = 0;
    int vs = 0;
    if (w < 4) {
        vs = wscan(my);
        if (lane == 63) wred[w] = vs;
    }
    __syncthreads();
    if (w < 4) {
        int addv = 0;
        #pragma unroll
        for (int i = 0; i < 3; ++i) addv += (i < w) ? wred[i] : 0;
        vs += addv;
        scnt[t] = vs;                              // global inclusive
        if (t < NSB) sbase[t] = vs - my;
    }
    __syncthreads();
    int total = scnt[NSB - 1];
    if (total > CAP) total = CAP;                  // defensive

    // --- Phase A2: direct per-run copy (no binary search) + node histogram.
    // Thread t (<196) owns producer run t: contiguous in buf, position
    // sbase[t]+k known from the A1 scan.
    if (t < NSB) {
        const int rb = rbase[t], sb = sbase[t];
        const unsigned* src = buf + (size_t)t * EPB + rb;
        for (int k = 0; k < my; ++k) {
            int pos = sb + k;
            if (pos < CAP) {
                unsigned pk = src[k];
                pkbuf[pos] = pk;
                atomicAdd(&hist[(pk >> 16) & (BS - 1)], 1);
            }
        }
    }
    __syncthreads();

    // --- Phase A3: 32-bin scan (single wave) + scatter into srt (local CSR)
    int hv = (t < BS) ? hist[t] : 0;
    int nv = 0;
    if (w == 0) nv = wscan(hv);
    __syncthreads();
    if (t < BS) { int ex = nv - hv; off[t] = ex; cur[t] = ex; }
    __syncthreads();
    for (int p = t; p < total; p += 512) {
        unsigned pk = pkbuf[p];
        int n = (pk >> 16) & (BS - 1);
        int pos = atomicAdd(&cur[n], 1);
        srt[pos] = (ushort)(pk & 0xffffu);
    }
    __syncthreads();

    // --- Phase B: per-quarter node ownership (R14-proven), 1 node/quarter.
    // quarter qq owns node n = w*4 + qq; 16 lanes x uint4 = full 256B row.
    const int qq = lane >> 4;
    const int sl = lane & 15;
    const uint4* nfv = (const uint4*)nfh;          // row = idx*16 uint4s

    {
        const int n = w * 4 + qq;
        const int beg = off[n], cnt = hist[n];
        f32x2 a0 = {0.f, 0.f}, a1 = {0.f, 0.f}, a2 = {0.f, 0.f}, a3 = {0.f, 0.f};
        int p = 0;
        for (; p + 2 <= cnt; p += 2) {             // 2 gathers in flight
            const int s0 = srt[beg + p];
            const int s1 = srt[beg + p + 1];
            const uint4 v0 = nfv[(size_t)s0 * 16 + sl];
            const uint4 v1 = nfv[(size_t)s1 * 16 + sl];
            acc8(a0, a1, a2, a3, v0);
            acc8(a0, a1, a2, a3, v1);
        }
        if (p < cnt) {                             // odd tail
            const int s0 = srt[beg + p];
            const uint4 v0 = nfv[(size_t)s0 * 16 + sl];
            acc8(a0, a1, a2, a3, v0);
        }
        uint4 o;                                   // all 64 lanes: 4 rows/wave
        o.x = (unsigned)f2bf(a0.x) | ((unsigned)f2bf(a0.y) << 16);
        o.y = (unsigned)f2bf(a1.x) | ((unsigned)f2bf(a1.y) << 16);
        o.z = (unsigned)f2bf(a2.x) | ((unsigned)f2bf(a2.y) << 16);
        o.w = (unsigned)f2bf(a3.x) | ((unsigned)f2bf(a3.y) << 16);
        *(uint4*)(tile + n * (AROWU / 2) + sl * 4) = o;
    }
    __syncthreads();

    // --- Phase C: 2 row-tiles x 8 col-chunks = 16 MFMA tasks over 8 waves
    const int m = lane & 15, q = lane >> 4;
    const ushort* lds = (const ushort*)tile;
    #pragma unroll
    for (int i = 0; i < 2; ++i) {
        const int task = w + 8 * i;                 // 0..15, bijective
        const int t16  = task >> 3;                 // row-tile 0..1
        const int c0   = (task & 7) * 16;           // col chunk
        const int grow0 = b * BS + t16 * 16;
        if (grow0 < NN) {                           // last bucket: 1 full tile
            bf16x8 a[4];
            const ushort* arow = lds + (t16 * 16 + m) * AROWU + q * 8;
            #pragma unroll
            for (int kk = 0; kk < 4; ++kk)
                a[kk] = *(const bf16x8*)(arow + kk * 32);
            float bv = bias[c0 + m];
            f32x4 acc4 = { bv, bv, bv, bv };
            const ushort* wrow = Wh + (size_t)(c0 + m) * D + q * 8;
            #pragma unroll
            for (int kk = 0; kk < 4; ++kk) {
                bf16x8 bb = *(const bf16x8*)(wrow + kk * 32);
                acc4 = __builtin_amdgcn_mfma_f32_16x16x32_bf16(a[kk], bb, acc4, 0, 0, 0);
            }
            float* op = out + (size_t)(grow0 + q * 4) * D + c0 + m;
            op[0]     = acc4[0];
            op[D]     = acc4[1];
            op[2 * D] = acc4[2];
            op[3 * D] = acc4[3];
        }
    }
}

extern "C" void kernel_launch(void* const* d_in, const int* in_sizes, int n_in,
                              void* d_out, int out_size, void* d_ws, size_t ws_size,
                              hipStream_t stream) {
    const float* nf = (const float*)d_in[0];
    const int*   ei = (const int*)d_in[1];
    const float* W  = (const float*)d_in[2];
    const float* b  = (const float*)d_in[3];
    float* out = (float*)d_out;

    // workspace (~16.7 MB)
    ushort*   nfh  = (ushort*)d_ws;                    // NN*D bf16 = 12.8 MB
    ushort*   Wh   = nfh + (size_t)NN * D;             // 32 KB
    unsigned* buf  = (unsigned*)(Wh + D * D);          // NSB*EPB u32 = 3.2 MB
    ushort*   offs = (ushort*)(buf + (size_t)NSB * EPB); // (NB+1)*NSB = 613 KB

    k_prep_bucket<<<GRID_A, 512, 0, stream>>>(nf, W, ei, nfh, Wh, offs, buf);
    k_sort_agg   <<<NB, 512, 0, stream>>>((const unsigned*)nfh, buf, offs, Wh, b, out);
}

// Round 10
// 128.607 us; speedup vs baseline: 1.2523x; 1.0241x over previous
//
#include <hip/hip_runtime.h>

// GNN layer: out = segment_sum(nf[src], dst) @ W.T + b
// N=50000, E=800000, D=128.
// R23: REVERT to R19 (best verified core: sort_agg 45.0us, total 126.7-128.3).
// R22's A-phase direct-copy regressed (48.4us): the binary search it replaced
// was already latency-hidden under co-resident blocks' Phase-B gathers.
// Final model: sort_agg is bound by the L2-miss gather path -- per-XCD L2
// footprint (~11MB) >> 4MB L2 makes ~87MB TCC-miss traffic compulsory
// (R16-verified), served at ~1.9-2.4 TB/s for random 256B rows -> ~45us.
// Falsified families: reg pipelines (compiler sinks, R15/16/17), async-LDS
// staging (consume overhead >= depth gain, R18/R21), locality windows (R16),
// co-residency (R20), A-phase shaves (R22). Structure: BS=32, 1563 blocks
// of 512thr (dynamic balancing, R19's win); B = per-quarter uint4 walk;
// C = 16x16x32 bf16 MFMA tiles.

constexpr int NN = 50000;
constexpr int NE = 800000;
constexpr int D  = 128;

constexpr int BS   = 32;                       // nodes per bucket
constexpr int NB   = (NN + BS - 1) / BS;       // 1563 buckets
constexpr int EPB  = 4096;                     // edges per producer block
constexpr int NSB  = (NE + EPB - 1) / EPB;     // 196 producer blocks
constexpr int CAP  = 1024;                     // per-bucket edge cap (avg 512)

constexpr int AROWU = 136;                     // tile row stride (ushorts)

typedef __attribute__((ext_vector_type(8))) short bf16x8;
typedef __attribute__((ext_vector_type(4))) float f32x4;
typedef __attribute__((ext_vector_type(2))) float f32x2;

__device__ inline unsigned short f2bf(float f) {           // RNE
    unsigned u = __float_as_uint(f);
    return (unsigned short)((u + 0x7fffu + ((u >> 16) & 1u)) >> 16);
}
__device__ inline float bflo(unsigned v) { return __uint_as_float(v << 16); }
__device__ inline float bfhi(unsigned v) { return __uint_as_float(v & 0xffff0000u); }

__device__ inline int wscan(int v) {           // wave-inclusive scan (64)
    #pragma unroll
    for (int o = 1; o < 64; o <<= 1) {
        int u = __shfl_up(v, o);
        if ((int)(threadIdx.x & 63) >= o) v += u;
    }
    return v;
}

__device__ inline void acc8(f32x2& a0, f32x2& a1, f32x2& a2, f32x2& a3, uint4 v) {
    a0 += (f32x2){bflo(v.x), bfhi(v.x)};
    a1 += (f32x2){bflo(v.y), bfhi(v.y)};
    a2 += (f32x2){bflo(v.z), bfhi(v.z)};
    a3 += (f32x2){bflo(v.w), bfhi(v.w)};
}

// ---- 1. fused prep (bf16 cvt) + bucket-sort partition ---------------------
constexpr int NF4 = NN * D / 4;                           // 1,600,000
constexpr int W4  = D * D / 4;                            // 4,096
constexpr int NBLK_P = (NF4 + W4 + 511) / 512;            // 3134
constexpr int GRID_A = NSB + NBLK_P;

__global__ __launch_bounds__(512) void k_prep_bucket(
    const float* __restrict__ nf, const float* __restrict__ W,
    const int* __restrict__ ei,
    ushort* __restrict__ nfh, ushort* __restrict__ Wh,
    ushort* __restrict__ offs, unsigned* __restrict__ buf)
{
    __shared__ int hist[NB], cur[NB];              // 12.5 KB
    __shared__ int wsum[8];
    __shared__ unsigned spk[EPB];                  // 16384 B
    const int t = threadIdx.x, lane = t & 63, w = t >> 6;

    if (blockIdx.x < NSB) {
        const int blk = blockIdx.x;
        const int e0  = blk * EPB;
        int cnt = NE - e0; if (cnt > EPB) cnt = EPB;

        for (int i = t; i < NB; i += 512) hist[i] = 0;
        __syncthreads();

        unsigned pk[8];
        #pragma unroll
        for (int j = 0; j < 8; ++j) {
            int idx = j * 512 + t;
            if (idx < cnt) {
                int e = e0 + idx;
                unsigned s = (unsigned)ei[e];
                unsigned d = (unsigned)ei[NE + e];
                pk[j] = (d << 16) | s;             // bucket = pk >> 21 (BS=32)
                atomicAdd(&hist[pk[j] >> 21], 1);
            }
        }
        __syncthreads();
        // 4-bins/thread wave shfl scan over 1563 bins
        const int base = 4 * t;
        int h0 = (base     < NB) ? hist[base]     : 0;
        int h1 = (base + 1 < NB) ? hist[base + 1] : 0;
        int h2 = (base + 2 < NB) ? hist[base + 2] : 0;
        int h3 = (base + 3 < NB) ? hist[base + 3] : 0;
        int s4 = h0 + h1 + h2 + h3;
        int v = wscan(s4);
        if (lane == 63) wsum[w] = v;
        __syncthreads();
        int addv = 0;
        #pragma unroll
        for (int i = 0; i < 8; ++i) addv += (i < w) ? wsum[i] : 0;
        v += addv;                                 // inclusive through base+3
        int e0b = v - s4, e1b = e0b + h0, e2b = e1b + h1, e3b = e2b + h2;
        if (base     < NB) { cur[base]     = e0b; offs[(base    ) * NSB + blk] = (ushort)e0b; }
        if (base + 1 < NB) { cur[base + 1] = e1b; offs[(base + 1) * NSB + blk] = (ushort)e1b; }
        if (base + 2 < NB) { cur[base + 2] = e2b; offs[(base + 2) * NSB + blk] = (ushort)e2b; }
        if (base + 3 < NB) { cur[base + 3] = e3b; offs[(base + 3) * NSB + blk] = (ushort)e3b; }
        if (t == 0) offs[NB * NSB + blk] = (ushort)cnt;
        __syncthreads();
        #pragma unroll
        for (int j = 0; j < 8; ++j) {
            int idx = j * 512 + t;
            if (idx < cnt) {
                int l = atomicAdd(&cur[pk[j] >> 21], 1);
                spk[l] = pk[j];
            }
        }
        __syncthreads();
        for (int i = t; i < cnt; i += 512)         // dense coalesced 16KB
            buf[(size_t)blk * EPB + i] = spk[i];
    } else {
        // prep branch: bf16 conversion
        int i = (blockIdx.x - NSB) * 512 + t;
        if (i < NF4) {
            float4 v = ((const float4*)nf)[i];
            ((ushort4*)nfh)[i] = make_ushort4(f2bf(v.x), f2bf(v.y), f2bf(v.z), f2bf(v.w));
        } else if (i < NF4 + W4) {
            int k = i - NF4;
            float4 v = ((const float4*)W)[k];
            ((ushort4*)Wh)[k] = make_ushort4(f2bf(v.x), f2bf(v.y), f2bf(v.z), f2bf(v.w));
        }
    }
}

// ---- 2. fused gather-sort + aggregate + linear ----------------------------
__global__ __launch_bounds__(512) void k_sort_agg(
    const unsigned* __restrict__ nfh, const unsigned* __restrict__ buf,
    const ushort* __restrict__ offs, const ushort* __restrict__ Wh,
    const float* __restrict__ bias, float* __restrict__ out)
{
    __shared__ ushort srt[CAP];                     // 2048 B
    __shared__ int scnt[256];                       // 1024 B
    __shared__ int sbase[NSB], rbase[NSB];          // 1568 B
    __shared__ int hist[BS], off[BS], cur[BS];      // 384 B
    __shared__ int wred[16];
    __shared__ __align__(16) unsigned tile[BS * AROWU / 2];  // 8704 B (~14KB)
    const int b = blockIdx.x, t = threadIdx.x;
    const int lane = t & 63, w = t >> 6;

    // --- Phase A1: per-producer run bases/counts -> wave shfl scan
    int my = 0;
    if (t < NSB) {
        int o0 = (int)offs[b * NSB + t];           // coalesced 392B row
        int o1 = (int)offs[(b + 1) * NSB + t];
        rbase[t] = o0;
        my = o1 - o0;
    }
    if (t < BS) hist[t] = 0;
    int vs = 0;
    if (w < 4) {
        vs = wscan(my);
        if (lane == 63) wred[w] = vs;
    }
    __syncthreads();
    if (w < 4) {
        int addv = 0;
        #pragma unroll
        for (int i = 0; i < 3; ++i) addv += (i < w) ? wred[i] : 0;
        vs += addv;
        scnt[t] = vs;                              // global inclusive
        if (t < NSB) sbase[t] = vs - my;
    }
    __syncthreads();
    int total = scnt[NSB - 1];
    if (total > CAP) total = CAP;                  // defensive

    // --- Phase A2: pk in registers + node histogram
    unsigned mypk[2];
    int mycnt = 0;
    #pragma unroll
    for (int j = 0; j < 2; ++j) {
        int p = t + j * 512;
        if (p < total) {
            int lo = 0, hi = NSB - 1;              // min i: scnt[i] > p
            while (lo < hi) {
                int mid = (lo + hi) >> 1;
                if (scnt[mid] > p) hi = mid; else lo = mid + 1;
            }
            unsigned pk = buf[(size_t)lo * EPB + rbase[lo] + (p - sbase[lo])];
            mypk[j] = pk;
            atomicAdd(&hist[(pk >> 16) & (BS - 1)], 1);
            mycnt = j + 1;
        }
    }
    __syncthreads();

    // --- Phase A3: 32-bin scan (single wave) + scatter into srt (local CSR)
    int hv = (t < BS) ? hist[t] : 0;
    int nv = 0;
    if (w == 0) nv = wscan(hv);
    __syncthreads();
    if (t < BS) { int ex = nv - hv; off[t] = ex; cur[t] = ex; }
    __syncthreads();
    #pragma unroll
    for (int j = 0; j < 2; ++j) {
        if (j < mycnt) {
            unsigned pk = mypk[j];
            int n = (pk >> 16) & (BS - 1);
            int p = atomicAdd(&cur[n], 1);
            srt[p] = (ushort)(pk & 0xffffu);
        }
    }
    __syncthreads();

    // --- Phase B: per-quarter node ownership (R14-proven), 1 node/quarter.
    // quarter qq owns node n = w*4 + qq; 16 lanes x uint4 = full 256B row.
    const int qq = lane >> 4;
    const int sl = lane & 15;
    const uint4* nfv = (const uint4*)nfh;          // row = idx*16 uint4s

    {
        const int n = w * 4 + qq;
        const int beg = off[n], cnt = hist[n];
        f32x2 a0 = {0.f, 0.f}, a1 = {0.f, 0.f}, a2 = {0.f, 0.f}, a3 = {0.f, 0.f};
        int p = 0;
        for (; p + 2 <= cnt; p += 2) {             // 2 gathers in flight
            const int s0 = srt[beg + p];
            const int s1 = srt[beg + p + 1];
            const uint4 v0 = nfv[(size_t)s0 * 16 + sl];
            const uint4 v1 = nfv[(size_t)s1 * 16 + sl];
            acc8(a0, a1, a2, a3, v0);
            acc8(a0, a1, a2, a3, v1);
        }
        if (p < cnt) {                             // odd tail
            const int s0 = srt[beg + p];
            const uint4 v0 = nfv[(size_t)s0 * 16 + sl];
            acc8(a0, a1, a2, a3, v0);
        }
        uint4 o;                                   // all 64 lanes: 4 rows/wave
        o.x = (unsigned)f2bf(a0.x) | ((unsigned)f2bf(a0.y) << 16);
        o.y = (unsigned)f2bf(a1.x) | ((unsigned)f2bf(a1.y) << 16);
        o.z = (unsigned)f2bf(a2.x) | ((unsigned)f2bf(a2.y) << 16);
        o.w = (unsigned)f2bf(a3.x) | ((unsigned)f2bf(a3.y) << 16);
        *(uint4*)(tile + n * (AROWU / 2) + sl * 4) = o;
    }
    __syncthreads();

    // --- Phase C: 2 row-tiles x 8 col-chunks = 16 MFMA tasks over 8 waves
    const int m = lane & 15, q = lane >> 4;
    const ushort* lds = (const ushort*)tile;
    #pragma unroll
    for (int i = 0; i < 2; ++i) {
        const int task = w + 8 * i;                 // 0..15, bijective
        const int t16  = task >> 3;                 // row-tile 0..1
        const int c0   = (task & 7) * 16;           // col chunk
        const int grow0 = b * BS + t16 * 16;
        if (grow0 < NN) {                           // last bucket: 1 full tile
            bf16x8 a[4];
            const ushort* arow = lds + (t16 * 16 + m) * AROWU + q * 8;
            #pragma unroll
            for (int kk = 0; kk < 4; ++kk)
                a[kk] = *(const bf16x8*)(arow + kk * 32);
            float bv = bias[c0 + m];
            f32x4 acc4 = { bv, bv, bv, bv };
            const ushort* wrow = Wh + (size_t)(c0 + m) * D + q * 8;
            #pragma unroll
            for (int kk = 0; kk < 4; ++kk) {
                bf16x8 bb = *(const bf16x8*)(wrow + kk * 32);
                acc4 = __builtin_amdgcn_mfma_f32_16x16x32_bf16(a[kk], bb, acc4, 0, 0, 0);
            }
            float* op = out + (size_t)(grow0 + q * 4) * D + c0 + m;
            op[0]     = acc4[0];
            op[D]     = acc4[1];
            op[2 * D] = acc4[2];
            op[3 * D] = acc4[3];
        }
    }
}

extern "C" void kernel_launch(void* const* d_in, const int* in_sizes, int n_in,
                              void* d_out, int out_size, void* d_ws, size_t ws_size,
                              hipStream_t stream) {
    const float* nf = (const float*)d_in[0];
    const int*   ei = (const int*)d_in[1];
    const float* W  = (const float*)d_in[2];
    const float* b  = (const float*)d_in[3];
    float* out = (float*)d_out;

    // workspace (~16.7 MB)
    ushort*   nfh  = (ushort*)d_ws;                    // NN*D bf16 = 12.8 MB
    ushort*   Wh   = nfh + (size_t)NN * D;             // 32 KB
    unsigned* buf  = (unsigned*)(Wh + D * D);          // NSB*EPB u32 = 3.2 MB
    ushort*   offs = (ushort*)(buf + (size_t)NSB * EPB); // (NB+1)*NSB = 613 KB

    k_prep_bucket<<<GRID_A, 512, 0, stream>>>(nf, W, ei, nfh, Wh, offs, buf);
    k_sort_agg   <<<NB, 512, 0, stream>>>((const unsigned*)nfh, buf, offs, Wh, b, out);
}